// Round 10
// baseline (766.215 us; speedup 1.0000x reference)
//
#include <hip/hip_runtime.h>

typedef __bf16 bf16;
typedef __bf16 bf16x8 __attribute__((ext_vector_type(8)));
typedef float f32x4 __attribute__((ext_vector_type(4)));
typedef unsigned u32x4 __attribute__((ext_vector_type(4)));

#define MFMA16(a, b, c) __builtin_amdgcn_mfma_f32_16x16x32_bf16((a), (b), (c), 0, 0, 0)

static __device__ __forceinline__ bf16x8 ldg8(const bf16* p) {
  return *(const bf16x8*)p;
}
static __device__ __forceinline__ unsigned cvt_pk_bf16(float lo, float hi) {
  unsigned d;
  asm("v_cvt_pk_bf16_f32 %0, %1, %2" : "=v"(d) : "v"(lo), "v"(hi));
  return d;
}
static __device__ __forceinline__ void pl32_swap(unsigned& a, unsigned& b) {
  asm("v_permlane32_swap_b32 %0, %1" : "+v"(a), "+v"(b));
}
static __device__ __forceinline__ void pl16_swap(unsigned& a, unsigned& b) {
  asm("v_permlane16_swap_b32 %0, %1" : "+v"(a), "+v"(b));
}

// ===========================================================================
// Ladder: 803 -> ... -> 191.2 (r7) -> 192.8 (r8 neutral) -> 191.7 (r9: XCD
// swizzle on flash: FETCH 73->15.9MB, dur FLAT -> flash is NOT memory-bound;
// it is structure/latency-bound at 4 waves/SIMD, MfmaUtil 40 VALU 45).
// r10: occupancy lever -- flash 4 -> 8 blocks/CU: KVBLK 64->32 (LDS 16KB,
// tile body == old per-h2 body, same work/kv), split x4 (grid 2048 = 8/CU
// exact, chunked XCD swizzle kept), launch_bounds(256,8) (VGPR cap 64 ==
// current measured usage). V-tile swizzle re-derived for 4-unit rows
// (write conflict-free, read 2-way=free). out_gemm staging sums 4 partials
// (r5-proven combine math inlined). ws: r5 overlay layout, end 60.29MB.
// Predict: flash Occ 33->~65, dur 82.9->70-76; total ~180-186. If flash
// flat, inner-loop structure is the confirmed ceiling.
// ===========================================================================

// ---- prep: bx<16 -> pack W (fp32 [K][N]) into P32T tiles (nt<12 Wqkv,
// else Wout); bx>=16 -> cvt x (fp32 [8192][512]) into P32 tiles Xp. ----
__global__ __launch_bounds__(256) void prep(const float* __restrict__ Wqkv,
                                            const float* __restrict__ Wout,
                                            const float* __restrict__ x,
                                            bf16* __restrict__ Wp1,
                                            bf16* __restrict__ Wp2,
                                            bf16* __restrict__ Xp) {
  __shared__ float tile[32 * 129];
  if (blockIdx.x < 16) {
    int kc = blockIdx.x, nt = blockIdx.y;
    const float* W;
    bf16* dst;
    int N, ntl;
    if (nt < 12) {
      W = Wqkv; N = 1536; ntl = nt;
      dst = Wp1 + ((size_t)ntl * 16 + kc) * 4096;
    } else {
      W = Wout; N = 512; ntl = nt - 12;
      dst = Wp2 + ((size_t)ntl * 16 + kc) * 4096;
    }
    int row = threadIdx.x >> 3;
    int c0 = (threadIdx.x & 7) * 16;
    const float* src = W + (size_t)(kc * 32 + row) * N + ntl * 128 + c0;
#pragma unroll
    for (int i = 0; i < 4; i++) {
      float4 v = *(const float4*)(src + i * 4);
      tile[row * 129 + c0 + i * 4 + 0] = v.x;
      tile[row * 129 + c0 + i * 4 + 1] = v.y;
      tile[row * 129 + c0 + i * 4 + 2] = v.z;
      tile[row * 129 + c0 + i * 4 + 3] = v.w;
    }
    __syncthreads();
#pragma unroll
    for (int half = 0; half < 2; half++) {
      int U = threadIdx.x + half * 256;
      int kchunk = U >> 7, n = U & 127;
      bf16x8 o;
#pragma unroll
      for (int j = 0; j < 8; j++) o[j] = (bf16)tile[(kchunk * 8 + j) * 129 + n];
      *(bf16x8*)&dst[U * 8] = o;
    }
  } else {
    // cvt_pack_x: tile(mt,kc)=128x32, addr = kchunk*1024 + r*8 + kk
    int mt = blockIdx.x - 16, kc = blockIdx.y;
    int r = threadIdx.x >> 1;
    int khalf = threadIdx.x & 1;
    const float* src = x + (size_t)(mt * 128 + r) * 512 + kc * 32 + khalf * 16;
    float4 v0 = *(const float4*)(src + 0);
    float4 v1 = *(const float4*)(src + 4);
    float4 v2 = *(const float4*)(src + 8);
    float4 v3 = *(const float4*)(src + 12);
    bf16* dt = Xp + ((size_t)mt * 16 + kc) * 4096;
    bf16x8 a, b;
    a[0] = (bf16)v0.x; a[1] = (bf16)v0.y; a[2] = (bf16)v0.z; a[3] = (bf16)v0.w;
    a[4] = (bf16)v1.x; a[5] = (bf16)v1.y; a[6] = (bf16)v1.z; a[7] = (bf16)v1.w;
    b[0] = (bf16)v2.x; b[1] = (bf16)v2.y; b[2] = (bf16)v2.z; b[3] = (bf16)v2.w;
    b[4] = (bf16)v3.x; b[5] = (bf16)v3.y; b[6] = (bf16)v3.z; b[7] = (bf16)v3.w;
    int kc0 = khalf * 2;
    *(bf16x8*)&dt[(kc0 + 0) * 1024 + r * 8] = a;
    *(bf16x8*)&dt[(kc0 + 1) * 1024 + r * 8] = b;
  }
}

// ---------------------------------------------------------------------------
// QKV projection (r7/r8-proven, unchanged), 128x128 tiles. Grid (64,12).
// A staged from packed Xp; B-frags direct ldg8 from Wp1. Epilogue: LDS
// round-trip, coalesced 16B stores. Q pre-scaled by 0.125*log2e.
// ---------------------------------------------------------------------------
__global__ __launch_bounds__(256, 3) void qkv_gemm(const bf16* __restrict__ Xp,
                                                   const bf16* __restrict__ Wp1,
                                                   const float* __restrict__ bqkv,
                                                   bf16* __restrict__ Q,
                                                   bf16* __restrict__ Kh,
                                                   bf16* __restrict__ Vt) {
  int mt = blockIdx.x, nt = blockIdx.y;
  int tid = threadIdx.x;
  int wave = tid >> 6, lane = tid & 63;
  int l16 = lane & 15, quad = lane >> 4;
  int wr = wave >> 1, wc = wave & 1;

  __shared__ __align__(16) bf16 SM[9216];  // A dbuf 2x4096; epilogue T 128x72

  const bf16* At = Xp + (size_t)mt * 16 * 4096;
  const bf16* Bt = Wp1 + (size_t)nt * 16 * 4096;

  bf16x8 pa0 = ldg8(At + tid * 8);
  bf16x8 pa1 = ldg8(At + 2048 + tid * 8);

  f32x4 acc[4][4] = {};
#pragma unroll 2
  for (int kc = 0; kc < 16; kc++) {
    bf16* A = SM + (kc & 1) * 4096;
    *(bf16x8*)&A[tid * 8] = pa0;
    *(bf16x8*)&A[2048 + tid * 8] = pa1;
    __syncthreads();
    if (kc < 15) {
      const bf16* an = At + (kc + 1) * 4096;
      pa0 = ldg8(an + tid * 8);
      pa1 = ldg8(an + 2048 + tid * 8);
    }
    bf16x8 af[4], bfr[4];
#pragma unroll
    for (int fi = 0; fi < 4; fi++)
      af[fi] = *(const bf16x8*)&A[(quad * 128 + wr * 64 + fi * 16 + l16) * 8];
    const bf16* Bk = Bt + kc * 4096;
#pragma unroll
    for (int fj = 0; fj < 4; fj++)
      bfr[fj] = ldg8(Bk + (quad * 128 + wc * 64 + fj * 16 + l16) * 8);
    __builtin_amdgcn_s_setprio(1);
#pragma unroll
    for (int fi = 0; fi < 4; fi++)
#pragma unroll
      for (int fj = 0; fj < 4; fj++)
        acc[fi][fj] = MFMA16(af[fi], bfr[fj], acc[fi][fj]);
    __builtin_amdgcn_s_setprio(0);
  }

  // ---- epilogue: LDS round-trip, coalesced 16B stores ----
  __syncthreads();
  const int TS = 72;
  int b = mt >> 5;

  if (nt < 8) {
    bool isQ = nt < 4;
    bf16* dstb = isQ ? Q : Kh;
    int hb = isQ ? nt * 2 : (nt - 4) * 2;
#pragma unroll
    for (int ph = 0; ph < 2; ph++) {
      if (wc == ph) {
#pragma unroll
        for (int fj = 0; fj < 4; fj++) {
          float bias = bqkv[nt * 128 + wc * 64 + fj * 16 + l16];
#pragma unroll
          for (int fi = 0; fi < 4; fi++)
#pragma unroll
            for (int rr = 0; rr < 4; rr++) {
              float v = acc[fi][fj][rr] + bias;
              if (isQ) v *= 0.18033688f;  // 0.125*log2e
              SM[(wr * 64 + fi * 16 + quad * 4 + rr) * TS + fj * 16 + l16] =
                  (bf16)v;
            }
        }
      }
      __syncthreads();
      int bh = b * 8 + hb + ph;
      bf16* dh = dstb + (size_t)bh * 4096 * 64 + (size_t)((mt & 31) * 128) * 64;
#pragma unroll
      for (int i = 0; i < 4; i++) {
        int U = tid + i * 256;
        int mr = U >> 3, oct = U & 7;
        bf16x8 v = ldg8(&SM[mr * TS + oct * 8]);
        *(bf16x8*)&dh[(size_t)mr * 64 + oct * 8] = v;
      }
      __syncthreads();
    }
  } else {
    int h0 = (nt - 8) * 2;
#pragma unroll
    for (int ph = 0; ph < 2; ph++) {
      if (wr == ph) {
#pragma unroll
        for (int fj = 0; fj < 4; fj++) {
          float bias = bqkv[nt * 128 + wc * 64 + fj * 16 + l16];
          int cp = wc * 64 + fj * 16 + l16;
#pragma unroll
          for (int fi = 0; fi < 4; fi++)
#pragma unroll
            for (int rr = 0; rr < 4; rr++)
              SM[cp * TS + fi * 16 + quad * 4 + rr] =
                  (bf16)(acc[fi][fj][rr] + bias);
        }
      }
      __syncthreads();
      int nb = (mt & 31) * 2 + ph;
#pragma unroll
      for (int i = 0; i < 4; i++) {
        int U = tid + i * 256;
        int cp = U >> 3, oct = U & 7;
        int h = h0 + (cp >> 6), d = cp & 63;
        int bh = b * 8 + h;
        bf16x8 v = ldg8(&SM[cp * TS + oct * 8]);
        *(bf16x8*)&Vt[(((size_t)bh * 64 + nb) * 64 + d) * 64 + oct * 8] = v;
      }
      __syncthreads();
    }
  }
}

// ---------------------------------------------------------------------------
// flash_partial v20: 8 blocks/CU. Grid 2048 (XCD chunked swizzle, each XCD
// owns 2 bh). Per block: (bh, strip of 128 q, qtr of 1024 kv), 32 KV-tiles
// of 32. Tile body == proven per-h2 body: QK(8 MFMA) -> SM -> PV+l(10).
// K tile [32][64] swz unit=r*8+(c^(r&7)); V tile [64][32] swz
// unit=d*4+(c^((d>>1)&3)) (write conflict-free, read 2-way=free).
// LDS 16KB, launch_bounds(256,8) = VGPR cap 64 (current measured usage).
// ---------------------------------------------------------------------------
__global__ __launch_bounds__(256, 8) void flash_partial(const bf16* __restrict__ Q,
                                                        const bf16* __restrict__ K,
                                                        const bf16* __restrict__ Vt,
                                                        bf16* __restrict__ Opart,
                                                        float* __restrict__ Lpart) {
  int i = blockIdx.x;
  int swz = (i & 7) * 256 + (i >> 3);  // bijective: 2048 % 8 == 0
  int qtr = swz & 3;
  int strip = (swz >> 2) & 31;
  int bh = swz >> 7;
  int tid = threadIdx.x;
  int wave = tid >> 6, lane = tid & 63;
  int l16 = lane & 15, quad = lane >> 4;

  const bf16* Qh = Q + (size_t)bh * 4096 * 64;
  const bf16* Kg = K + ((size_t)bh * 4096 + qtr * 1024) * 64;
  const bf16* Vg = Vt + (size_t)bh * 64 * 4096 + (size_t)qtr * 1024 * 64;

  __shared__ __align__(16) bf16 Klds[2][2048];
  __shared__ __align__(16) bf16 Vlds[2][2048];

  int qbase = strip * 128 + wave * 32;
  bf16x8 aq[2][2];
#pragma unroll
  for (int mt = 0; mt < 2; mt++) {
    const bf16* qr = Qh + (size_t)(qbase + mt * 16 + l16) * 64;
    aq[mt][0] = ldg8(qr + quad * 8);
    aq[mt][1] = ldg8(qr + 32 + quad * 8);
  }

  bf16x8 ones;
#pragma unroll
  for (int j = 0; j < 8; j++) ones[j] = (bf16)1.0f;

  f32x4 o[2][4] = {};
  f32x4 acc_l[2] = {};

  // staging units (swizzled, conflict-free writes)
  int ku = (tid >> 3) * 8 + ((tid & 7) ^ ((tid >> 3) & 7));
  int vd = tid >> 2, vc8 = (tid & 3) * 8;
  int vu = vd * 4 + ((tid & 3) ^ ((vd >> 1) & 3));

  bf16x8 kp = ldg8(Kg + tid * 8);
  bf16x8 vp = ldg8(Vg + (size_t)vd * 64 + vc8);

#pragma unroll 2
  for (int t = 0; t < 32; t++) {
    bf16* kl = Klds[t & 1];
    bf16* vl = Vlds[t & 1];
    *(bf16x8*)&kl[ku * 8] = kp;
    *(bf16x8*)&vl[vu * 8] = vp;
    __syncthreads();

    if (t < 31) {
      kp = ldg8(Kg + (size_t)(t + 1) * 2048 + tid * 8);
      vp = ldg8(Vg + (size_t)((t + 1) >> 1) * 4096 + ((t + 1) & 1) * 32 +
                (size_t)vd * 64 + vc8);
    }

    // ---- S^T = K Q^T (swapped operands), 32 kv ----
    f32x4 s[2][2] = {};
    __builtin_amdgcn_s_setprio(1);
#pragma unroll
    for (int c2 = 0; c2 < 2; c2++) {
      int n = c2 * 16 + l16;  // kv row in tile
      bf16x8 k0 = *(const bf16x8*)&kl[(n * 8 + (quad ^ (n & 7))) * 8];
      bf16x8 k1 = *(const bf16x8*)&kl[(n * 8 + ((4 + quad) ^ (n & 7))) * 8];
#pragma unroll
      for (int mt = 0; mt < 2; mt++) {
        s[mt][c2] = MFMA16(k0, aq[mt][0], s[mt][c2]);
        s[mt][c2] = MFMA16(k1, aq[mt][1], s[mt][c2]);
      }
    }
    __builtin_amdgcn_s_setprio(0);

    // ---- p = exp2(s); pack+redistribute to PV A-frags ----
    bf16x8 pa[2];
#pragma unroll
    for (int mt = 0; mt < 2; mt++) {
      unsigned ue[2], wo[2];
#pragma unroll
      for (int c2 = 0; c2 < 2; c2++) {
        float p0 = __builtin_amdgcn_exp2f(s[mt][c2][0]);
        float p1 = __builtin_amdgcn_exp2f(s[mt][c2][1]);
        float p2 = __builtin_amdgcn_exp2f(s[mt][c2][2]);
        float p3 = __builtin_amdgcn_exp2f(s[mt][c2][3]);
        ue[c2] = cvt_pk_bf16(p0, p1);
        wo[c2] = cvt_pk_bf16(p2, p3);
      }
      pl32_swap(ue[0], ue[1]);
      pl16_swap(ue[0], ue[1]);
      pl32_swap(wo[0], wo[1]);
      pl16_swap(wo[0], wo[1]);
      u32x4 pk = {ue[0], wo[0], ue[1], wo[1]};
      pa[mt] = __builtin_bit_cast(bf16x8, pk);
    }

    // ---- O += P V; l += P ones ----
    __builtin_amdgcn_s_setprio(1);
    acc_l[0] = MFMA16(pa[0], ones, acc_l[0]);
    acc_l[1] = MFMA16(pa[1], ones, acc_l[1]);
#pragma unroll
    for (int ct = 0; ct < 4; ct++) {
      int d = ct * 16 + l16;
      bf16x8 bv = *(const bf16x8*)&vl[(d * 4 + (quad ^ ((d >> 1) & 3))) * 8];
      o[0][ct] = MFMA16(pa[0], bv, o[0][ct]);
      o[1][ct] = MFMA16(pa[1], bv, o[1][ct]);
    }
    __builtin_amdgcn_s_setprio(0);
  }

  // ---- epilogue: partial o (bf16) + l (fp32, shuffle-free) ----
  size_t ub = ((size_t)qtr * 16 + bh) * 32 + strip;
  bf16* op = Opart + ub * 8192;
#pragma unroll
  for (int mt = 0; mt < 2; mt++) {
#pragma unroll
    for (int ct = 0; ct < 4; ct++)
#pragma unroll
      for (int r = 0; r < 4; r++)
        op[(wave * 32 + mt * 16 + quad * 4 + r) * 64 + ct * 16 + l16] =
            (bf16)o[mt][ct][r];
    if (l16 == 0) {
#pragma unroll
      for (int r = 0; r < 4; r++)
        Lpart[ub * 128 + wave * 32 + mt * 16 + quad * 4 + r] = acc_l[mt][r];
    }
  }
}

// ---------------------------------------------------------------------------
// Output projection + FUSED 4-way combine: 64x128 tiles, grid (128 mt, 4 nt)
// = 512 blocks = 2/CU. A-staging computes sum_q(o_q)/sum_q(l_q) from
// Opart/Lpart (r5-proven combine math). B-frags direct ldg8 from Wp2.
// ---------------------------------------------------------------------------
__global__ __launch_bounds__(256, 4) void out_gemm(const bf16* __restrict__ Opart,
                                                   const float* __restrict__ Lpart,
                                                   const bf16* __restrict__ Wp2,
                                                   const float* __restrict__ bout,
                                                   float* __restrict__ Out) {
  int mt = blockIdx.x, nt = blockIdx.y;
  int tid = threadIdx.x;
  int wave = tid >> 6, lane = tid & 63;
  int l16 = lane & 15, quad = lane >> 4;
  int mt128 = mt >> 1, mhalf = mt & 1;
  int b = mt128 >> 5, strip = mt128 & 31;
  int r = mhalf * 64 + lane;

  __shared__ __align__(16) bf16 SM[2][2048];

  const bf16* Bt = Wp2 + (size_t)nt * 16 * 4096;

  bf16x8 po[4];
  float pls;
  {
    int bh = b * 8;  // kc = 0: h = 0, d0 = 0
    pls = 0.f;
#pragma unroll
    for (int q = 0; q < 4; q++) {
      size_t u = ((size_t)q * 16 + bh) * 32 + strip;
      po[q] = ldg8(&Opart[u * 8192 + r * 64 + wave * 8]);
      pls += Lpart[u * 128 + r];
    }
  }

  f32x4 acc[4][2] = {};
#pragma unroll 2
  for (int kc = 0; kc < 16; kc++) {
    bf16* A = SM[kc & 1];
    float rl = 1.0f / pls;
    float sj[8];
#pragma unroll
    for (int j = 0; j < 8; j++)
      sj[j] = (((float)po[0][j] + (float)po[1][j]) +
               ((float)po[2][j] + (float)po[3][j])) * rl;
    u32x4 pk = {cvt_pk_bf16(sj[0], sj[1]), cvt_pk_bf16(sj[2], sj[3]),
                cvt_pk_bf16(sj[4], sj[5]), cvt_pk_bf16(sj[6], sj[7])};
    *(bf16x8*)&A[tid * 8] = __builtin_bit_cast(bf16x8, pk);
    __syncthreads();
    if (kc < 15) {
      int kn = kc + 1;
      int h = kn >> 1, d0 = (kn & 1) * 32;
      int bh = b * 8 + h;
      pls = 0.f;
#pragma unroll
      for (int q = 0; q < 4; q++) {
        size_t u = ((size_t)q * 16 + bh) * 32 + strip;
        po[q] = ldg8(&Opart[u * 8192 + r * 64 + d0 + wave * 8]);
        pls += Lpart[u * 128 + r];
      }
    }
    bf16x8 af[4], bfr[2];
#pragma unroll
    for (int fi = 0; fi < 4; fi++)
      af[fi] = *(const bf16x8*)&A[(quad * 64 + fi * 16 + l16) * 8];
    const bf16* Bk = Bt + kc * 4096;
#pragma unroll
    for (int fj = 0; fj < 2; fj++)
      bfr[fj] = ldg8(Bk + (quad * 128 + wave * 32 + fj * 16 + l16) * 8);
    __builtin_amdgcn_s_setprio(1);
#pragma unroll
    for (int fi = 0; fi < 4; fi++)
#pragma unroll
      for (int fj = 0; fj < 2; fj++)
        acc[fi][fj] = MFMA16(af[fi], bfr[fj], acc[fi][fj]);
    __builtin_amdgcn_s_setprio(0);
  }

#pragma unroll
  for (int fj = 0; fj < 2; fj++) {
    int c = nt * 128 + wave * 32 + fj * 16 + l16;
    float bias = bout[c];
#pragma unroll
    for (int fi = 0; fi < 4; fi++) {
#pragma unroll
      for (int rr = 0; rr < 4; rr++) {
        int m = mt * 64 + fi * 16 + quad * 4 + rr;
        Out[(size_t)m * 512 + c] = acc[fi][fj][rr] + bias;
      }
    }
  }
}

// ---------------------------------------------------------------------------
// ws layout (lifetime-overlapped, r5-proven; end 60,293,120 < 61.4MB):
//   Q 0 (8.39M) | K 8388608 | Vt 16777216 | Wp2 25165824 (0.52M) |
//   Opart 25690112 (33.55M) | Lpart 59244544 (1.05M)
//   Xp 25690112 (8.39M, dead after qkv) | Wp1 34078720 (1.57M, dead after
//   qkv) -- both inside Opart region, clobbered only when flash writes it.
// ---------------------------------------------------------------------------
extern "C" void kernel_launch(void* const* d_in, const int* in_sizes, int n_in,
                              void* d_out, int out_size, void* d_ws,
                              size_t ws_size, hipStream_t stream) {
  const float* x = (const float*)d_in[0];
  const float* w_qkv = (const float*)d_in[1];
  const float* b_qkv = (const float*)d_in[2];
  const float* w_out = (const float*)d_in[3];
  const float* b_out = (const float*)d_in[4];
  float* out = (float*)d_out;

  char* ws = (char*)d_ws;
  bf16* Q = (bf16*)(ws + 0);
  bf16* K = (bf16*)(ws + 8388608);
  bf16* Vt = (bf16*)(ws + 16777216);
  bf16* Wp2 = (bf16*)(ws + 25165824);
  bf16* Opart = (bf16*)(ws + 25690112);
  float* Lpart = (float*)(ws + 59244544);
  bf16* Xp = (bf16*)(ws + 25690112);   // overlays Opart region, dead pre-flash
  bf16* Wp1 = (bf16*)(ws + 34078720);  // overlays Opart region, dead pre-flash

  prep<<<dim3(80, 16), 256, 0, stream>>>(w_qkv, w_out, x, Wp1, Wp2, Xp);
  qkv_gemm<<<dim3(64, 12), 256, 0, stream>>>(Xp, Wp1, b_qkv, Q, K, Vt);
  flash_partial<<<dim3(2048), 256, 0, stream>>>(Q, K, Vt, Opart, Lpart);
  out_gemm<<<dim3(128, 4), 256, 0, stream>>>(Opart, Lpart, Wp2, b_out, out);
}

// Round 11
// 192.860 us; speedup vs baseline: 3.9729x; 3.9729x over previous
//
#include <hip/hip_runtime.h>

typedef __bf16 bf16;
typedef __bf16 bf16x8 __attribute__((ext_vector_type(8)));
typedef float f32x4 __attribute__((ext_vector_type(4)));
typedef unsigned u32x4 __attribute__((ext_vector_type(4)));

#define MFMA16(a, b, c) __builtin_amdgcn_mfma_f32_16x16x32_bf16((a), (b), (c), 0, 0, 0)

static __device__ __forceinline__ bf16x8 ldg8(const bf16* p) {
  return *(const bf16x8*)p;
}
static __device__ __forceinline__ unsigned cvt_pk_bf16(float lo, float hi) {
  unsigned d;
  asm("v_cvt_pk_bf16_f32 %0, %1, %2" : "=v"(d) : "v"(lo), "v"(hi));
  return d;
}
static __device__ __forceinline__ void pl32_swap(unsigned& a, unsigned& b) {
  asm("v_permlane32_swap_b32 %0, %1" : "+v"(a), "+v"(b));
}
static __device__ __forceinline__ void pl16_swap(unsigned& a, unsigned& b) {
  asm("v_permlane16_swap_b32 %0, %1" : "+v"(a), "+v"(b));
}

// ===========================================================================
// Ladder: 803 -> ... -> 191.2 (r7) -> 191.7 (r9: XCD swizzle, FETCH 73->16MB
// proving flash latency-bound) -> r10 766us FAILED: launch_bounds(256,8)
// forced VGPR cap ~64 -> allocator emitted 32 -> 3GB scratch spill (FETCH
// 1.46GB, Mfma 4.7%). Occupancy itself reached 82% and numerics passed.
// r11 = r10 with the ONE fix: launch_bounds(256,4) (cap 128; allocator
// naturally ~64) -> residency bounded by LDS 16KB / wave slots / VGPR=64
// = 8 blocks/CU WITHOUT constraining the allocator (G1). Everything else
// identical to r10 (KVBLK=32, grid 2048 XCD-chunked, 4-way combine in
// out_gemm, r5 overlay ws). If flash still ~83 at high occupancy, the
// serial inner-loop is the confirmed ceiling -> revert & stop.
// ===========================================================================

// ---- prep: bx<16 -> pack W (fp32 [K][N]) into P32T tiles (nt<12 Wqkv,
// else Wout); bx>=16 -> cvt x (fp32 [8192][512]) into P32 tiles Xp. ----
__global__ __launch_bounds__(256) void prep(const float* __restrict__ Wqkv,
                                            const float* __restrict__ Wout,
                                            const float* __restrict__ x,
                                            bf16* __restrict__ Wp1,
                                            bf16* __restrict__ Wp2,
                                            bf16* __restrict__ Xp) {
  __shared__ float tile[32 * 129];
  if (blockIdx.x < 16) {
    int kc = blockIdx.x, nt = blockIdx.y;
    const float* W;
    bf16* dst;
    int N, ntl;
    if (nt < 12) {
      W = Wqkv; N = 1536; ntl = nt;
      dst = Wp1 + ((size_t)ntl * 16 + kc) * 4096;
    } else {
      W = Wout; N = 512; ntl = nt - 12;
      dst = Wp2 + ((size_t)ntl * 16 + kc) * 4096;
    }
    int row = threadIdx.x >> 3;
    int c0 = (threadIdx.x & 7) * 16;
    const float* src = W + (size_t)(kc * 32 + row) * N + ntl * 128 + c0;
#pragma unroll
    for (int i = 0; i < 4; i++) {
      float4 v = *(const float4*)(src + i * 4);
      tile[row * 129 + c0 + i * 4 + 0] = v.x;
      tile[row * 129 + c0 + i * 4 + 1] = v.y;
      tile[row * 129 + c0 + i * 4 + 2] = v.z;
      tile[row * 129 + c0 + i * 4 + 3] = v.w;
    }
    __syncthreads();
#pragma unroll
    for (int half = 0; half < 2; half++) {
      int U = threadIdx.x + half * 256;
      int kchunk = U >> 7, n = U & 127;
      bf16x8 o;
#pragma unroll
      for (int j = 0; j < 8; j++) o[j] = (bf16)tile[(kchunk * 8 + j) * 129 + n];
      *(bf16x8*)&dst[U * 8] = o;
    }
  } else {
    // cvt_pack_x: tile(mt,kc)=128x32, addr = kchunk*1024 + r*8 + kk
    int mt = blockIdx.x - 16, kc = blockIdx.y;
    int r = threadIdx.x >> 1;
    int khalf = threadIdx.x & 1;
    const float* src = x + (size_t)(mt * 128 + r) * 512 + kc * 32 + khalf * 16;
    float4 v0 = *(const float4*)(src + 0);
    float4 v1 = *(const float4*)(src + 4);
    float4 v2 = *(const float4*)(src + 8);
    float4 v3 = *(const float4*)(src + 12);
    bf16* dt = Xp + ((size_t)mt * 16 + kc) * 4096;
    bf16x8 a, b;
    a[0] = (bf16)v0.x; a[1] = (bf16)v0.y; a[2] = (bf16)v0.z; a[3] = (bf16)v0.w;
    a[4] = (bf16)v1.x; a[5] = (bf16)v1.y; a[6] = (bf16)v1.z; a[7] = (bf16)v1.w;
    b[0] = (bf16)v2.x; b[1] = (bf16)v2.y; b[2] = (bf16)v2.z; b[3] = (bf16)v2.w;
    b[4] = (bf16)v3.x; b[5] = (bf16)v3.y; b[6] = (bf16)v3.z; b[7] = (bf16)v3.w;
    int kc0 = khalf * 2;
    *(bf16x8*)&dt[(kc0 + 0) * 1024 + r * 8] = a;
    *(bf16x8*)&dt[(kc0 + 1) * 1024 + r * 8] = b;
  }
}

// ---------------------------------------------------------------------------
// QKV projection (r7/r8-proven, unchanged), 128x128 tiles. Grid (64,12).
// A staged from packed Xp; B-frags direct ldg8 from Wp1. Epilogue: LDS
// round-trip, coalesced 16B stores. Q pre-scaled by 0.125*log2e.
// ---------------------------------------------------------------------------
__global__ __launch_bounds__(256, 3) void qkv_gemm(const bf16* __restrict__ Xp,
                                                   const bf16* __restrict__ Wp1,
                                                   const float* __restrict__ bqkv,
                                                   bf16* __restrict__ Q,
                                                   bf16* __restrict__ Kh,
                                                   bf16* __restrict__ Vt) {
  int mt = blockIdx.x, nt = blockIdx.y;
  int tid = threadIdx.x;
  int wave = tid >> 6, lane = tid & 63;
  int l16 = lane & 15, quad = lane >> 4;
  int wr = wave >> 1, wc = wave & 1;

  __shared__ __align__(16) bf16 SM[9216];  // A dbuf 2x4096; epilogue T 128x72

  const bf16* At = Xp + (size_t)mt * 16 * 4096;
  const bf16* Bt = Wp1 + (size_t)nt * 16 * 4096;

  bf16x8 pa0 = ldg8(At + tid * 8);
  bf16x8 pa1 = ldg8(At + 2048 + tid * 8);

  f32x4 acc[4][4] = {};
#pragma unroll 2
  for (int kc = 0; kc < 16; kc++) {
    bf16* A = SM + (kc & 1) * 4096;
    *(bf16x8*)&A[tid * 8] = pa0;
    *(bf16x8*)&A[2048 + tid * 8] = pa1;
    __syncthreads();
    if (kc < 15) {
      const bf16* an = At + (kc + 1) * 4096;
      pa0 = ldg8(an + tid * 8);
      pa1 = ldg8(an + 2048 + tid * 8);
    }
    bf16x8 af[4], bfr[4];
#pragma unroll
    for (int fi = 0; fi < 4; fi++)
      af[fi] = *(const bf16x8*)&A[(quad * 128 + wr * 64 + fi * 16 + l16) * 8];
    const bf16* Bk = Bt + kc * 4096;
#pragma unroll
    for (int fj = 0; fj < 4; fj++)
      bfr[fj] = ldg8(Bk + (quad * 128 + wc * 64 + fj * 16 + l16) * 8);
    __builtin_amdgcn_s_setprio(1);
#pragma unroll
    for (int fi = 0; fi < 4; fi++)
#pragma unroll
      for (int fj = 0; fj < 4; fj++)
        acc[fi][fj] = MFMA16(af[fi], bfr[fj], acc[fi][fj]);
    __builtin_amdgcn_s_setprio(0);
  }

  // ---- epilogue: LDS round-trip, coalesced 16B stores ----
  __syncthreads();
  const int TS = 72;
  int b = mt >> 5;

  if (nt < 8) {
    bool isQ = nt < 4;
    bf16* dstb = isQ ? Q : Kh;
    int hb = isQ ? nt * 2 : (nt - 4) * 2;
#pragma unroll
    for (int ph = 0; ph < 2; ph++) {
      if (wc == ph) {
#pragma unroll
        for (int fj = 0; fj < 4; fj++) {
          float bias = bqkv[nt * 128 + wc * 64 + fj * 16 + l16];
#pragma unroll
          for (int fi = 0; fi < 4; fi++)
#pragma unroll
            for (int rr = 0; rr < 4; rr++) {
              float v = acc[fi][fj][rr] + bias;
              if (isQ) v *= 0.18033688f;  // 0.125*log2e
              SM[(wr * 64 + fi * 16 + quad * 4 + rr) * TS + fj * 16 + l16] =
                  (bf16)v;
            }
        }
      }
      __syncthreads();
      int bh = b * 8 + hb + ph;
      bf16* dh = dstb + (size_t)bh * 4096 * 64 + (size_t)((mt & 31) * 128) * 64;
#pragma unroll
      for (int i = 0; i < 4; i++) {
        int U = tid + i * 256;
        int mr = U >> 3, oct = U & 7;
        bf16x8 v = ldg8(&SM[mr * TS + oct * 8]);
        *(bf16x8*)&dh[(size_t)mr * 64 + oct * 8] = v;
      }
      __syncthreads();
    }
  } else {
    int h0 = (nt - 8) * 2;
#pragma unroll
    for (int ph = 0; ph < 2; ph++) {
      if (wr == ph) {
#pragma unroll
        for (int fj = 0; fj < 4; fj++) {
          float bias = bqkv[nt * 128 + wc * 64 + fj * 16 + l16];
          int cp = wc * 64 + fj * 16 + l16;
#pragma unroll
          for (int fi = 0; fi < 4; fi++)
#pragma unroll
            for (int rr = 0; rr < 4; rr++)
              SM[cp * TS + fi * 16 + quad * 4 + rr] =
                  (bf16)(acc[fi][fj][rr] + bias);
        }
      }
      __syncthreads();
      int nb = (mt & 31) * 2 + ph;
#pragma unroll
      for (int i = 0; i < 4; i++) {
        int U = tid + i * 256;
        int cp = U >> 3, oct = U & 7;
        int h = h0 + (cp >> 6), d = cp & 63;
        int bh = b * 8 + h;
        bf16x8 v = ldg8(&SM[cp * TS + oct * 8]);
        *(bf16x8*)&Vt[(((size_t)bh * 64 + nb) * 64 + d) * 64 + oct * 8] = v;
      }
      __syncthreads();
    }
  }
}

// ---------------------------------------------------------------------------
// flash_partial v21 (= r10 structure, launch_bounds FIXED to (256,4)):
// Grid 2048, XCD chunked swizzle (each XCD owns 2 bh). Per block:
// (bh, strip 128 q, qtr 1024 kv), 32 KV-tiles of 32. Tile body = proven
// per-h2 body: QK(8 MFMA) -> SM -> PV+l(10). LDS 16KB; VGPR ~64 natural
// -> 8 blocks/CU via LDS/wave-slot/VGPR limits, NOT allocator cap (G1;
// r10's (256,8) forced 32 VGPR -> 3GB spill).
// ---------------------------------------------------------------------------
__global__ __launch_bounds__(256, 4) void flash_partial(const bf16* __restrict__ Q,
                                                        const bf16* __restrict__ K,
                                                        const bf16* __restrict__ Vt,
                                                        bf16* __restrict__ Opart,
                                                        float* __restrict__ Lpart) {
  int i = blockIdx.x;
  int swz = (i & 7) * 256 + (i >> 3);  // bijective: 2048 % 8 == 0
  int qtr = swz & 3;
  int strip = (swz >> 2) & 31;
  int bh = swz >> 7;
  int tid = threadIdx.x;
  int wave = tid >> 6, lane = tid & 63;
  int l16 = lane & 15, quad = lane >> 4;

  const bf16* Qh = Q + (size_t)bh * 4096 * 64;
  const bf16* Kg = K + ((size_t)bh * 4096 + qtr * 1024) * 64;
  const bf16* Vg = Vt + (size_t)bh * 64 * 4096 + (size_t)qtr * 1024 * 64;

  __shared__ __align__(16) bf16 Klds[2][2048];
  __shared__ __align__(16) bf16 Vlds[2][2048];

  int qbase = strip * 128 + wave * 32;
  bf16x8 aq[2][2];
#pragma unroll
  for (int mt = 0; mt < 2; mt++) {
    const bf16* qr = Qh + (size_t)(qbase + mt * 16 + l16) * 64;
    aq[mt][0] = ldg8(qr + quad * 8);
    aq[mt][1] = ldg8(qr + 32 + quad * 8);
  }

  bf16x8 ones;
#pragma unroll
  for (int j = 0; j < 8; j++) ones[j] = (bf16)1.0f;

  f32x4 o[2][4] = {};
  f32x4 acc_l[2] = {};

  // staging units (swizzled, conflict-free writes)
  int ku = (tid >> 3) * 8 + ((tid & 7) ^ ((tid >> 3) & 7));
  int vd = tid >> 2, vc8 = (tid & 3) * 8;
  int vu = vd * 4 + ((tid & 3) ^ ((vd >> 1) & 3));

  bf16x8 kp = ldg8(Kg + tid * 8);
  bf16x8 vp = ldg8(Vg + (size_t)vd * 64 + vc8);

#pragma unroll 2
  for (int t = 0; t < 32; t++) {
    bf16* kl = Klds[t & 1];
    bf16* vl = Vlds[t & 1];
    *(bf16x8*)&kl[ku * 8] = kp;
    *(bf16x8*)&vl[vu * 8] = vp;
    __syncthreads();

    if (t < 31) {
      kp = ldg8(Kg + (size_t)(t + 1) * 2048 + tid * 8);
      vp = ldg8(Vg + (size_t)((t + 1) >> 1) * 4096 + ((t + 1) & 1) * 32 +
                (size_t)vd * 64 + vc8);
    }

    // ---- S^T = K Q^T (swapped operands), 32 kv ----
    f32x4 s[2][2] = {};
    __builtin_amdgcn_s_setprio(1);
#pragma unroll
    for (int c2 = 0; c2 < 2; c2++) {
      int n = c2 * 16 + l16;  // kv row in tile
      bf16x8 k0 = *(const bf16x8*)&kl[(n * 8 + (quad ^ (n & 7))) * 8];
      bf16x8 k1 = *(const bf16x8*)&kl[(n * 8 + ((4 + quad) ^ (n & 7))) * 8];
#pragma unroll
      for (int mt = 0; mt < 2; mt++) {
        s[mt][c2] = MFMA16(k0, aq[mt][0], s[mt][c2]);
        s[mt][c2] = MFMA16(k1, aq[mt][1], s[mt][c2]);
      }
    }
    __builtin_amdgcn_s_setprio(0);

    // ---- p = exp2(s); pack+redistribute to PV A-frags ----
    bf16x8 pa[2];
#pragma unroll
    for (int mt = 0; mt < 2; mt++) {
      unsigned ue[2], wo[2];
#pragma unroll
      for (int c2 = 0; c2 < 2; c2++) {
        float p0 = __builtin_amdgcn_exp2f(s[mt][c2][0]);
        float p1 = __builtin_amdgcn_exp2f(s[mt][c2][1]);
        float p2 = __builtin_amdgcn_exp2f(s[mt][c2][2]);
        float p3 = __builtin_amdgcn_exp2f(s[mt][c2][3]);
        ue[c2] = cvt_pk_bf16(p0, p1);
        wo[c2] = cvt_pk_bf16(p2, p3);
      }
      pl32_swap(ue[0], ue[1]);
      pl16_swap(ue[0], ue[1]);
      pl32_swap(wo[0], wo[1]);
      pl16_swap(wo[0], wo[1]);
      u32x4 pk = {ue[0], wo[0], ue[1], wo[1]};
      pa[mt] = __builtin_bit_cast(bf16x8, pk);
    }

    // ---- O += P V; l += P ones ----
    __builtin_amdgcn_s_setprio(1);
    acc_l[0] = MFMA16(pa[0], ones, acc_l[0]);
    acc_l[1] = MFMA16(pa[1], ones, acc_l[1]);
#pragma unroll
    for (int ct = 0; ct < 4; ct++) {
      int d = ct * 16 + l16;
      bf16x8 bv = *(const bf16x8*)&vl[(d * 4 + (quad ^ ((d >> 1) & 3))) * 8];
      o[0][ct] = MFMA16(pa[0], bv, o[0][ct]);
      o[1][ct] = MFMA16(pa[1], bv, o[1][ct]);
    }
    __builtin_amdgcn_s_setprio(0);
  }

  // ---- epilogue: partial o (bf16) + l (fp32, shuffle-free) ----
  size_t ub = ((size_t)qtr * 16 + bh) * 32 + strip;
  bf16* op = Opart + ub * 8192;
#pragma unroll
  for (int mt = 0; mt < 2; mt++) {
#pragma unroll
    for (int ct = 0; ct < 4; ct++)
#pragma unroll
      for (int r = 0; r < 4; r++)
        op[(wave * 32 + mt * 16 + quad * 4 + r) * 64 + ct * 16 + l16] =
            (bf16)o[mt][ct][r];
    if (l16 == 0) {
#pragma unroll
      for (int r = 0; r < 4; r++)
        Lpart[ub * 128 + wave * 32 + mt * 16 + quad * 4 + r] = acc_l[mt][r];
    }
  }
}

// ---------------------------------------------------------------------------
// Output projection + FUSED 4-way combine: 64x128 tiles, grid (128 mt, 4 nt)
// = 512 blocks = 2/CU. A-staging computes sum_q(o_q)/sum_q(l_q) from
// Opart/Lpart (r5-proven combine math). B-frags direct ldg8 from Wp2.
// ---------------------------------------------------------------------------
__global__ __launch_bounds__(256, 4) void out_gemm(const bf16* __restrict__ Opart,
                                                   const float* __restrict__ Lpart,
                                                   const bf16* __restrict__ Wp2,
                                                   const float* __restrict__ bout,
                                                   float* __restrict__ Out) {
  int mt = blockIdx.x, nt = blockIdx.y;
  int tid = threadIdx.x;
  int wave = tid >> 6, lane = tid & 63;
  int l16 = lane & 15, quad = lane >> 4;
  int mt128 = mt >> 1, mhalf = mt & 1;
  int b = mt128 >> 5, strip = mt128 & 31;
  int r = mhalf * 64 + lane;

  __shared__ __align__(16) bf16 SM[2][2048];

  const bf16* Bt = Wp2 + (size_t)nt * 16 * 4096;

  bf16x8 po[4];
  float pls;
  {
    int bh = b * 8;  // kc = 0: h = 0, d0 = 0
    pls = 0.f;
#pragma unroll
    for (int q = 0; q < 4; q++) {
      size_t u = ((size_t)q * 16 + bh) * 32 + strip;
      po[q] = ldg8(&Opart[u * 8192 + r * 64 + wave * 8]);
      pls += Lpart[u * 128 + r];
    }
  }

  f32x4 acc[4][2] = {};
#pragma unroll 2
  for (int kc = 0; kc < 16; kc++) {
    bf16* A = SM[kc & 1];
    float rl = 1.0f / pls;
    float sj[8];
#pragma unroll
    for (int j = 0; j < 8; j++)
      sj[j] = (((float)po[0][j] + (float)po[1][j]) +
               ((float)po[2][j] + (float)po[3][j])) * rl;
    u32x4 pk = {cvt_pk_bf16(sj[0], sj[1]), cvt_pk_bf16(sj[2], sj[3]),
                cvt_pk_bf16(sj[4], sj[5]), cvt_pk_bf16(sj[6], sj[7])};
    *(bf16x8*)&A[tid * 8] = __builtin_bit_cast(bf16x8, pk);
    __syncthreads();
    if (kc < 15) {
      int kn = kc + 1;
      int h = kn >> 1, d0 = (kn & 1) * 32;
      int bh = b * 8 + h;
      pls = 0.f;
#pragma unroll
      for (int q = 0; q < 4; q++) {
        size_t u = ((size_t)q * 16 + bh) * 32 + strip;
        po[q] = ldg8(&Opart[u * 8192 + r * 64 + d0 + wave * 8]);
        pls += Lpart[u * 128 + r];
      }
    }
    bf16x8 af[4], bfr[2];
#pragma unroll
    for (int fi = 0; fi < 4; fi++)
      af[fi] = *(const bf16x8*)&A[(quad * 64 + fi * 16 + l16) * 8];
    const bf16* Bk = Bt + kc * 4096;
#pragma unroll
    for (int fj = 0; fj < 2; fj++)
      bfr[fj] = ldg8(Bk + (quad * 128 + wave * 32 + fj * 16 + l16) * 8);
    __builtin_amdgcn_s_setprio(1);
#pragma unroll
    for (int fi = 0; fi < 4; fi++)
#pragma unroll
      for (int fj = 0; fj < 2; fj++)
        acc[fi][fj] = MFMA16(af[fi], bfr[fj], acc[fi][fj]);
    __builtin_amdgcn_s_setprio(0);
  }

#pragma unroll
  for (int fj = 0; fj < 2; fj++) {
    int c = nt * 128 + wave * 32 + fj * 16 + l16;
    float bias = bout[c];
#pragma unroll
    for (int fi = 0; fi < 4; fi++) {
#pragma unroll
      for (int rr = 0; rr < 4; rr++) {
        int m = mt * 64 + fi * 16 + quad * 4 + rr;
        Out[(size_t)m * 512 + c] = acc[fi][fj][rr] + bias;
      }
    }
  }
}

// ---------------------------------------------------------------------------
// ws layout (lifetime-overlapped, r5-proven; end 60,293,120 < 61.4MB):
//   Q 0 (8.39M) | K 8388608 | Vt 16777216 | Wp2 25165824 (0.52M) |
//   Opart 25690112 (33.55M) | Lpart 59244544 (1.05M)
//   Xp 25690112 (8.39M, dead after qkv) | Wp1 34078720 (1.57M, dead after
//   qkv) -- both inside Opart region, clobbered only when flash writes it.
// ---------------------------------------------------------------------------
extern "C" void kernel_launch(void* const* d_in, const int* in_sizes, int n_in,
                              void* d_out, int out_size, void* d_ws,
                              size_t ws_size, hipStream_t stream) {
  const float* x = (const float*)d_in[0];
  const float* w_qkv = (const float*)d_in[1];
  const float* b_qkv = (const float*)d_in[2];
  const float* w_out = (const float*)d_in[3];
  const float* b_out = (const float*)d_in[4];
  float* out = (float*)d_out;

  char* ws = (char*)d_ws;
  bf16* Q = (bf16*)(ws + 0);
  bf16* K = (bf16*)(ws + 8388608);
  bf16* Vt = (bf16*)(ws + 16777216);
  bf16* Wp2 = (bf16*)(ws + 25165824);
  bf16* Opart = (bf16*)(ws + 25690112);
  float* Lpart = (float*)(ws + 59244544);
  bf16* Xp = (bf16*)(ws + 25690112);   // overlays Opart region, dead pre-flash
  bf16* Wp1 = (bf16*)(ws + 34078720);  // overlays Opart region, dead pre-flash

  prep<<<dim3(80, 16), 256, 0, stream>>>(w_qkv, w_out, x, Wp1, Wp2, Xp);
  qkv_gemm<<<dim3(64, 12), 256, 0, stream>>>(Xp, Wp1, b_qkv, Q, K, Vt);
  flash_partial<<<dim3(2048), 256, 0, stream>>>(Q, K, Vt, Opart, Lpart);
  out_gemm<<<dim3(128, 4), 256, 0, stream>>>(Opart, Lpart, Wp2, b_out, out);
}

// Round 12
// 190.461 us; speedup vs baseline: 4.0229x; 1.0126x over previous
//
#include <hip/hip_runtime.h>

typedef __bf16 bf16;
typedef __bf16 bf16x8 __attribute__((ext_vector_type(8)));
typedef float f32x4 __attribute__((ext_vector_type(4)));
typedef unsigned u32x4 __attribute__((ext_vector_type(4)));

#define MFMA16(a, b, c) __builtin_amdgcn_mfma_f32_16x16x32_bf16((a), (b), (c), 0, 0, 0)

static __device__ __forceinline__ bf16x8 ldg8(const bf16* p) {
  return *(const bf16x8*)p;
}
static __device__ __forceinline__ unsigned cvt_pk_bf16(float lo, float hi) {
  unsigned d;
  asm("v_cvt_pk_bf16_f32 %0, %1, %2" : "=v"(d) : "v"(lo), "v"(hi));
  return d;
}
static __device__ __forceinline__ void pl32_swap(unsigned& a, unsigned& b) {
  asm("v_permlane32_swap_b32 %0, %1" : "+v"(a), "+v"(b));
}
static __device__ __forceinline__ void pl16_swap(unsigned& a, unsigned& b) {
  asm("v_permlane16_swap_b32 %0, %1" : "+v"(a), "+v"(b));
}

// ===========================================================================
// Ladder: 803 -> ... -> 191.2 (r7 best) -> r10 766 (forced-launch_bounds
// spill) -> r11 192.9 (fix; flash invariant ~81.5 across ALL occupancy/
// swizzle configs; Mfma 41 + VALU 51 = 92% issue-saturated; exp2 arithmetic
// ~55us floor -> flash FROZEN). "Others" ~111 vs ~75 model; dispatch-ID
// spacing shows ~40 harness memsets/iter = fixed cost. r12 (last lever):
// B-frag register prefetch in qkv+out (prime before loop, reload right
// after MFMA cluster -- no VGPR growth, shrinks exposed L2 latency; the
// barrier blocks compiler hoisting of the old in-loop loads). All else
// identical to r11. If delta <2us -> ceiling is confirmed.
// ===========================================================================

// ---- prep: bx<16 -> pack W (fp32 [K][N]) into P32T tiles (nt<12 Wqkv,
// else Wout); bx>=16 -> cvt x (fp32 [8192][512]) into P32 tiles Xp. ----
__global__ __launch_bounds__(256) void prep(const float* __restrict__ Wqkv,
                                            const float* __restrict__ Wout,
                                            const float* __restrict__ x,
                                            bf16* __restrict__ Wp1,
                                            bf16* __restrict__ Wp2,
                                            bf16* __restrict__ Xp) {
  __shared__ float tile[32 * 129];
  if (blockIdx.x < 16) {
    int kc = blockIdx.x, nt = blockIdx.y;
    const float* W;
    bf16* dst;
    int N, ntl;
    if (nt < 12) {
      W = Wqkv; N = 1536; ntl = nt;
      dst = Wp1 + ((size_t)ntl * 16 + kc) * 4096;
    } else {
      W = Wout; N = 512; ntl = nt - 12;
      dst = Wp2 + ((size_t)ntl * 16 + kc) * 4096;
    }
    int row = threadIdx.x >> 3;
    int c0 = (threadIdx.x & 7) * 16;
    const float* src = W + (size_t)(kc * 32 + row) * N + ntl * 128 + c0;
#pragma unroll
    for (int i = 0; i < 4; i++) {
      float4 v = *(const float4*)(src + i * 4);
      tile[row * 129 + c0 + i * 4 + 0] = v.x;
      tile[row * 129 + c0 + i * 4 + 1] = v.y;
      tile[row * 129 + c0 + i * 4 + 2] = v.z;
      tile[row * 129 + c0 + i * 4 + 3] = v.w;
    }
    __syncthreads();
#pragma unroll
    for (int half = 0; half < 2; half++) {
      int U = threadIdx.x + half * 256;
      int kchunk = U >> 7, n = U & 127;
      bf16x8 o;
#pragma unroll
      for (int j = 0; j < 8; j++) o[j] = (bf16)tile[(kchunk * 8 + j) * 129 + n];
      *(bf16x8*)&dst[U * 8] = o;
    }
  } else {
    // cvt_pack_x: tile(mt,kc)=128x32, addr = kchunk*1024 + r*8 + kk
    int mt = blockIdx.x - 16, kc = blockIdx.y;
    int r = threadIdx.x >> 1;
    int khalf = threadIdx.x & 1;
    const float* src = x + (size_t)(mt * 128 + r) * 512 + kc * 32 + khalf * 16;
    float4 v0 = *(const float4*)(src + 0);
    float4 v1 = *(const float4*)(src + 4);
    float4 v2 = *(const float4*)(src + 8);
    float4 v3 = *(const float4*)(src + 12);
    bf16* dt = Xp + ((size_t)mt * 16 + kc) * 4096;
    bf16x8 a, b;
    a[0] = (bf16)v0.x; a[1] = (bf16)v0.y; a[2] = (bf16)v0.z; a[3] = (bf16)v0.w;
    a[4] = (bf16)v1.x; a[5] = (bf16)v1.y; a[6] = (bf16)v1.z; a[7] = (bf16)v1.w;
    b[0] = (bf16)v2.x; b[1] = (bf16)v2.y; b[2] = (bf16)v2.z; b[3] = (bf16)v2.w;
    b[4] = (bf16)v3.x; b[5] = (bf16)v3.y; b[6] = (bf16)v3.z; b[7] = (bf16)v3.w;
    int kc0 = khalf * 2;
    *(bf16x8*)&dt[(kc0 + 0) * 1024 + r * 8] = a;
    *(bf16x8*)&dt[(kc0 + 1) * 1024 + r * 8] = b;
  }
}

// ---------------------------------------------------------------------------
// QKV projection, 128x128 tiles. Grid (64,12). A staged from packed Xp
// (one-barrier dbuf); B-frags register-prefetched one k-step ahead
// (primed pre-loop, reloaded right AFTER the MFMA cluster -> pb regs dead,
// no VGPR growth; old in-loop loads couldn't be hoisted past the barrier).
// Epilogue: LDS round-trip, coalesced 16B stores. Q pre-scaled 0.125*log2e.
// ---------------------------------------------------------------------------
__global__ __launch_bounds__(256, 3) void qkv_gemm(const bf16* __restrict__ Xp,
                                                   const bf16* __restrict__ Wp1,
                                                   const float* __restrict__ bqkv,
                                                   bf16* __restrict__ Q,
                                                   bf16* __restrict__ Kh,
                                                   bf16* __restrict__ Vt) {
  int mt = blockIdx.x, nt = blockIdx.y;
  int tid = threadIdx.x;
  int wave = tid >> 6, lane = tid & 63;
  int l16 = lane & 15, quad = lane >> 4;
  int wr = wave >> 1, wc = wave & 1;

  __shared__ __align__(16) bf16 SM[9216];  // A dbuf 2x4096; epilogue T 128x72

  const bf16* At = Xp + (size_t)mt * 16 * 4096;
  const bf16* Bt = Wp1 + (size_t)nt * 16 * 4096;

  bf16x8 pa0 = ldg8(At + tid * 8);
  bf16x8 pa1 = ldg8(At + 2048 + tid * 8);
  int boff[4];
#pragma unroll
  for (int fj = 0; fj < 4; fj++)
    boff[fj] = (quad * 128 + wc * 64 + fj * 16 + l16) * 8;
  bf16x8 pb[4];
#pragma unroll
  for (int fj = 0; fj < 4; fj++) pb[fj] = ldg8(Bt + boff[fj]);

  f32x4 acc[4][4] = {};
#pragma unroll 2
  for (int kc = 0; kc < 16; kc++) {
    bf16* A = SM + (kc & 1) * 4096;
    *(bf16x8*)&A[tid * 8] = pa0;
    *(bf16x8*)&A[2048 + tid * 8] = pa1;
    __syncthreads();
    if (kc < 15) {
      const bf16* an = At + (kc + 1) * 4096;
      pa0 = ldg8(an + tid * 8);
      pa1 = ldg8(an + 2048 + tid * 8);
    }
    bf16x8 af[4];
#pragma unroll
    for (int fi = 0; fi < 4; fi++)
      af[fi] = *(const bf16x8*)&A[(quad * 128 + wr * 64 + fi * 16 + l16) * 8];
    __builtin_amdgcn_s_setprio(1);
#pragma unroll
    for (int fi = 0; fi < 4; fi++)
#pragma unroll
      for (int fj = 0; fj < 4; fj++)
        acc[fi][fj] = MFMA16(af[fi], pb[fj], acc[fi][fj]);
    __builtin_amdgcn_s_setprio(0);
    if (kc < 15) {  // prefetch B(kc+1) AFTER last use of pb
      const bf16* bn = Bt + (kc + 1) * 4096;
#pragma unroll
      for (int fj = 0; fj < 4; fj++) pb[fj] = ldg8(bn + boff[fj]);
    }
  }

  // ---- epilogue: LDS round-trip, coalesced 16B stores ----
  __syncthreads();
  const int TS = 72;
  int b = mt >> 5;

  if (nt < 8) {
    bool isQ = nt < 4;
    bf16* dstb = isQ ? Q : Kh;
    int hb = isQ ? nt * 2 : (nt - 4) * 2;
#pragma unroll
    for (int ph = 0; ph < 2; ph++) {
      if (wc == ph) {
#pragma unroll
        for (int fj = 0; fj < 4; fj++) {
          float bias = bqkv[nt * 128 + wc * 64 + fj * 16 + l16];
#pragma unroll
          for (int fi = 0; fi < 4; fi++)
#pragma unroll
            for (int rr = 0; rr < 4; rr++) {
              float v = acc[fi][fj][rr] + bias;
              if (isQ) v *= 0.18033688f;  // 0.125*log2e
              SM[(wr * 64 + fi * 16 + quad * 4 + rr) * TS + fj * 16 + l16] =
                  (bf16)v;
            }
        }
      }
      __syncthreads();
      int bh = b * 8 + hb + ph;
      bf16* dh = dstb + (size_t)bh * 4096 * 64 + (size_t)((mt & 31) * 128) * 64;
#pragma unroll
      for (int i = 0; i < 4; i++) {
        int U = tid + i * 256;
        int mr = U >> 3, oct = U & 7;
        bf16x8 v = ldg8(&SM[mr * TS + oct * 8]);
        *(bf16x8*)&dh[(size_t)mr * 64 + oct * 8] = v;
      }
      __syncthreads();
    }
  } else {
    int h0 = (nt - 8) * 2;
#pragma unroll
    for (int ph = 0; ph < 2; ph++) {
      if (wr == ph) {
#pragma unroll
        for (int fj = 0; fj < 4; fj++) {
          float bias = bqkv[nt * 128 + wc * 64 + fj * 16 + l16];
          int cp = wc * 64 + fj * 16 + l16;
#pragma unroll
          for (int fi = 0; fi < 4; fi++)
#pragma unroll
            for (int rr = 0; rr < 4; rr++)
              SM[cp * TS + fi * 16 + quad * 4 + rr] =
                  (bf16)(acc[fi][fj][rr] + bias);
        }
      }
      __syncthreads();
      int nb = (mt & 31) * 2 + ph;
#pragma unroll
      for (int i = 0; i < 4; i++) {
        int U = tid + i * 256;
        int cp = U >> 3, oct = U & 7;
        int h = h0 + (cp >> 6), d = cp & 63;
        int bh = b * 8 + h;
        bf16x8 v = ldg8(&SM[cp * TS + oct * 8]);
        *(bf16x8*)&Vt[(((size_t)bh * 64 + nb) * 64 + d) * 64 + oct * 8] = v;
      }
      __syncthreads();
    }
  }
}

// ---------------------------------------------------------------------------
// flash_partial (r11, FROZEN): Grid 2048, XCD chunked swizzle. Per block:
// (bh, strip 128 q, qtr 1024 kv), 32 KV-tiles of 32. QK(8 MFMA) -> SM ->
// PV+l(10). In-reg P, exp2, ones-MFMA rowsum. K/V dbuf, one barrier/tile.
// launch_bounds(256,4): VGPR natural ~56; residency via LDS/slots (G1).
// ---------------------------------------------------------------------------
__global__ __launch_bounds__(256, 4) void flash_partial(const bf16* __restrict__ Q,
                                                        const bf16* __restrict__ K,
                                                        const bf16* __restrict__ Vt,
                                                        bf16* __restrict__ Opart,
                                                        float* __restrict__ Lpart) {
  int i = blockIdx.x;
  int swz = (i & 7) * 256 + (i >> 3);  // bijective: 2048 % 8 == 0
  int qtr = swz & 3;
  int strip = (swz >> 2) & 31;
  int bh = swz >> 7;
  int tid = threadIdx.x;
  int wave = tid >> 6, lane = tid & 63;
  int l16 = lane & 15, quad = lane >> 4;

  const bf16* Qh = Q + (size_t)bh * 4096 * 64;
  const bf16* Kg = K + ((size_t)bh * 4096 + qtr * 1024) * 64;
  const bf16* Vg = Vt + (size_t)bh * 64 * 4096 + (size_t)qtr * 1024 * 64;

  __shared__ __align__(16) bf16 Klds[2][2048];
  __shared__ __align__(16) bf16 Vlds[2][2048];

  int qbase = strip * 128 + wave * 32;
  bf16x8 aq[2][2];
#pragma unroll
  for (int mt = 0; mt < 2; mt++) {
    const bf16* qr = Qh + (size_t)(qbase + mt * 16 + l16) * 64;
    aq[mt][0] = ldg8(qr + quad * 8);
    aq[mt][1] = ldg8(qr + 32 + quad * 8);
  }

  bf16x8 ones;
#pragma unroll
  for (int j = 0; j < 8; j++) ones[j] = (bf16)1.0f;

  f32x4 o[2][4] = {};
  f32x4 acc_l[2] = {};

  // staging units (swizzled, conflict-free writes)
  int ku = (tid >> 3) * 8 + ((tid & 7) ^ ((tid >> 3) & 7));
  int vd = tid >> 2, vc8 = (tid & 3) * 8;
  int vu = vd * 4 + ((tid & 3) ^ ((vd >> 1) & 3));

  bf16x8 kp = ldg8(Kg + tid * 8);
  bf16x8 vp = ldg8(Vg + (size_t)vd * 64 + vc8);

#pragma unroll 2
  for (int t = 0; t < 32; t++) {
    bf16* kl = Klds[t & 1];
    bf16* vl = Vlds[t & 1];
    *(bf16x8*)&kl[ku * 8] = kp;
    *(bf16x8*)&vl[vu * 8] = vp;
    __syncthreads();

    if (t < 31) {
      kp = ldg8(Kg + (size_t)(t + 1) * 2048 + tid * 8);
      vp = ldg8(Vg + (size_t)((t + 1) >> 1) * 4096 + ((t + 1) & 1) * 32 +
                (size_t)vd * 64 + vc8);
    }

    // ---- S^T = K Q^T (swapped operands), 32 kv ----
    f32x4 s[2][2] = {};
    __builtin_amdgcn_s_setprio(1);
#pragma unroll
    for (int c2 = 0; c2 < 2; c2++) {
      int n = c2 * 16 + l16;  // kv row in tile
      bf16x8 k0 = *(const bf16x8*)&kl[(n * 8 + (quad ^ (n & 7))) * 8];
      bf16x8 k1 = *(const bf16x8*)&kl[(n * 8 + ((4 + quad) ^ (n & 7))) * 8];
#pragma unroll
      for (int mt = 0; mt < 2; mt++) {
        s[mt][c2] = MFMA16(k0, aq[mt][0], s[mt][c2]);
        s[mt][c2] = MFMA16(k1, aq[mt][1], s[mt][c2]);
      }
    }
    __builtin_amdgcn_s_setprio(0);

    // ---- p = exp2(s); pack+redistribute to PV A-frags ----
    bf16x8 pa[2];
#pragma unroll
    for (int mt = 0; mt < 2; mt++) {
      unsigned ue[2], wo[2];
#pragma unroll
      for (int c2 = 0; c2 < 2; c2++) {
        float p0 = __builtin_amdgcn_exp2f(s[mt][c2][0]);
        float p1 = __builtin_amdgcn_exp2f(s[mt][c2][1]);
        float p2 = __builtin_amdgcn_exp2f(s[mt][c2][2]);
        float p3 = __builtin_amdgcn_exp2f(s[mt][c2][3]);
        ue[c2] = cvt_pk_bf16(p0, p1);
        wo[c2] = cvt_pk_bf16(p2, p3);
      }
      pl32_swap(ue[0], ue[1]);
      pl16_swap(ue[0], ue[1]);
      pl32_swap(wo[0], wo[1]);
      pl16_swap(wo[0], wo[1]);
      u32x4 pk = {ue[0], wo[0], ue[1], wo[1]};
      pa[mt] = __builtin_bit_cast(bf16x8, pk);
    }

    // ---- O += P V; l += P ones ----
    __builtin_amdgcn_s_setprio(1);
    acc_l[0] = MFMA16(pa[0], ones, acc_l[0]);
    acc_l[1] = MFMA16(pa[1], ones, acc_l[1]);
#pragma unroll
    for (int ct = 0; ct < 4; ct++) {
      int d = ct * 16 + l16;
      bf16x8 bv = *(const bf16x8*)&vl[(d * 4 + (quad ^ ((d >> 1) & 3))) * 8];
      o[0][ct] = MFMA16(pa[0], bv, o[0][ct]);
      o[1][ct] = MFMA16(pa[1], bv, o[1][ct]);
    }
    __builtin_amdgcn_s_setprio(0);
  }

  // ---- epilogue: partial o (bf16) + l (fp32, shuffle-free) ----
  size_t ub = ((size_t)qtr * 16 + bh) * 32 + strip;
  bf16* op = Opart + ub * 8192;
#pragma unroll
  for (int mt = 0; mt < 2; mt++) {
#pragma unroll
    for (int ct = 0; ct < 4; ct++)
#pragma unroll
      for (int r = 0; r < 4; r++)
        op[(wave * 32 + mt * 16 + quad * 4 + r) * 64 + ct * 16 + l16] =
            (bf16)o[mt][ct][r];
    if (l16 == 0) {
#pragma unroll
      for (int r = 0; r < 4; r++)
        Lpart[ub * 128 + wave * 32 + mt * 16 + quad * 4 + r] = acc_l[mt][r];
    }
  }
}

// ---------------------------------------------------------------------------
// Output projection + FUSED 4-way combine: 64x128 tiles, grid (128, 4) =
// 512 blocks = 2/CU. A-staging computes sum_q(o_q)/sum_q(l_q) from Opart/
// Lpart. B-frags register-prefetched one k-step ahead (same pattern as qkv).
// ---------------------------------------------------------------------------
__global__ __launch_bounds__(256, 4) void out_gemm(const bf16* __restrict__ Opart,
                                                   const float* __restrict__ Lpart,
                                                   const bf16* __restrict__ Wp2,
                                                   const float* __restrict__ bout,
                                                   float* __restrict__ Out) {
  int mt = blockIdx.x, nt = blockIdx.y;
  int tid = threadIdx.x;
  int wave = tid >> 6, lane = tid & 63;
  int l16 = lane & 15, quad = lane >> 4;
  int mt128 = mt >> 1, mhalf = mt & 1;
  int b = mt128 >> 5, strip = mt128 & 31;
  int r = mhalf * 64 + lane;

  __shared__ __align__(16) bf16 SM[2][2048];

  const bf16* Bt = Wp2 + (size_t)nt * 16 * 4096;

  int boff[2];
#pragma unroll
  for (int fj = 0; fj < 2; fj++)
    boff[fj] = (quad * 128 + wave * 32 + fj * 16 + l16) * 8;
  bf16x8 pbo[2];
#pragma unroll
  for (int fj = 0; fj < 2; fj++) pbo[fj] = ldg8(Bt + boff[fj]);

  bf16x8 po[4];
  float pls;
  {
    int bh = b * 8;  // kc = 0: h = 0, d0 = 0
    pls = 0.f;
#pragma unroll
    for (int q = 0; q < 4; q++) {
      size_t u = ((size_t)q * 16 + bh) * 32 + strip;
      po[q] = ldg8(&Opart[u * 8192 + r * 64 + wave * 8]);
      pls += Lpart[u * 128 + r];
    }
  }

  f32x4 acc[4][2] = {};
#pragma unroll 2
  for (int kc = 0; kc < 16; kc++) {
    bf16* A = SM[kc & 1];
    float rl = 1.0f / pls;
    float sj[8];
#pragma unroll
    for (int j = 0; j < 8; j++)
      sj[j] = (((float)po[0][j] + (float)po[1][j]) +
               ((float)po[2][j] + (float)po[3][j])) * rl;
    u32x4 pk = {cvt_pk_bf16(sj[0], sj[1]), cvt_pk_bf16(sj[2], sj[3]),
                cvt_pk_bf16(sj[4], sj[5]), cvt_pk_bf16(sj[6], sj[7])};
    *(bf16x8*)&A[tid * 8] = __builtin_bit_cast(bf16x8, pk);
    __syncthreads();
    if (kc < 15) {
      int kn = kc + 1;
      int h = kn >> 1, d0 = (kn & 1) * 32;
      int bh = b * 8 + h;
      pls = 0.f;
#pragma unroll
      for (int q = 0; q < 4; q++) {
        size_t u = ((size_t)q * 16 + bh) * 32 + strip;
        po[q] = ldg8(&Opart[u * 8192 + r * 64 + d0 + wave * 8]);
        pls += Lpart[u * 128 + r];
      }
    }
    bf16x8 af[4];
#pragma unroll
    for (int fi = 0; fi < 4; fi++)
      af[fi] = *(const bf16x8*)&A[(quad * 64 + fi * 16 + l16) * 8];
    __builtin_amdgcn_s_setprio(1);
#pragma unroll
    for (int fi = 0; fi < 4; fi++)
#pragma unroll
      for (int fj = 0; fj < 2; fj++)
        acc[fi][fj] = MFMA16(af[fi], pbo[fj], acc[fi][fj]);
    __builtin_amdgcn_s_setprio(0);
    if (kc < 15) {  // prefetch B(kc+1) AFTER last use of pbo
      const bf16* bn = Bt + (kc + 1) * 4096;
#pragma unroll
      for (int fj = 0; fj < 2; fj++) pbo[fj] = ldg8(bn + boff[fj]);
    }
  }

#pragma unroll
  for (int fj = 0; fj < 2; fj++) {
    int c = nt * 128 + wave * 32 + fj * 16 + l16;
    float bias = bout[c];
#pragma unroll
    for (int fi = 0; fi < 4; fi++) {
#pragma unroll
      for (int rr = 0; rr < 4; rr++) {
        int m = mt * 64 + fi * 16 + quad * 4 + rr;
        Out[(size_t)m * 512 + c] = acc[fi][fj][rr] + bias;
      }
    }
  }
}

// ---------------------------------------------------------------------------
// ws layout (lifetime-overlapped, r5-proven; end 60,293,120 < 61.4MB):
//   Q 0 (8.39M) | K 8388608 | Vt 16777216 | Wp2 25165824 (0.52M) |
//   Opart 25690112 (33.55M) | Lpart 59244544 (1.05M)
//   Xp 25690112 (8.39M, dead after qkv) | Wp1 34078720 (1.57M, dead after
//   qkv) -- both inside Opart region, clobbered only when flash writes it.
// ---------------------------------------------------------------------------
extern "C" void kernel_launch(void* const* d_in, const int* in_sizes, int n_in,
                              void* d_out, int out_size, void* d_ws,
                              size_t ws_size, hipStream_t stream) {
  const float* x = (const float*)d_in[0];
  const float* w_qkv = (const float*)d_in[1];
  const float* b_qkv = (const float*)d_in[2];
  const float* w_out = (const float*)d_in[3];
  const float* b_out = (const float*)d_in[4];
  float* out = (float*)d_out;

  char* ws = (char*)d_ws;
  bf16* Q = (bf16*)(ws + 0);
  bf16* K = (bf16*)(ws + 8388608);
  bf16* Vt = (bf16*)(ws + 16777216);
  bf16* Wp2 = (bf16*)(ws + 25165824);
  bf16* Opart = (bf16*)(ws + 25690112);
  float* Lpart = (float*)(ws + 59244544);
  bf16* Xp = (bf16*)(ws + 25690112);   // overlays Opart region, dead pre-flash
  bf16* Wp1 = (bf16*)(ws + 34078720);  // overlays Opart region, dead pre-flash

  prep<<<dim3(80, 16), 256, 0, stream>>>(w_qkv, w_out, x, Wp1, Wp2, Xp);
  qkv_gemm<<<dim3(64, 12), 256, 0, stream>>>(Xp, Wp1, b_qkv, Q, K, Vt);
  flash_partial<<<dim3(2048), 256, 0, stream>>>(Q, K, Vt, Opart, Lpart);
  out_gemm<<<dim3(128, 4), 256, 0, stream>>>(Opart, Lpart, Wp2, b_out, out);
}